// Round 1
// 723.378 us; speedup vs baseline: 1.2751x; 1.2751x over previous
//
#include <hip/hip_runtime.h>
#include <math.h>

#define BB 8
#define SS 1024
#define DD 768
#define HH 12
#define DEP 64

typedef __attribute__((ext_vector_type(8))) short short8;
typedef __attribute__((ext_vector_type(4))) float floatx4;

// round-to-nearest-even fp32 -> bf16 (bit pattern in ushort)
static __device__ __forceinline__ unsigned short f2bf(float x) {
    union { float f; unsigned u; } v; v.f = x;
    unsigned r = v.u + 0x7fffu + ((v.u >> 16) & 1u);
    return (unsigned short)(r >> 16);
}

// ---------------------------------------------------------------------------
// fp32 -> bf16 conversion for q,k,v inputs (each N1=6291456 elems, /4 exact)
// ---------------------------------------------------------------------------
__global__ __launch_bounds__(256) void conv_inputs_kernel(
    const float* __restrict__ q, const float* __restrict__ k,
    const float* __restrict__ v,
    unsigned short* __restrict__ qb, unsigned short* __restrict__ kb,
    unsigned short* __restrict__ vb)
{
    const int y = blockIdx.y;
    const float* src = (y == 0) ? q : (y == 1) ? k : v;
    unsigned short* dst = (y == 0) ? qb : (y == 1) ? kb : vb;
    const size_t i = ((size_t)blockIdx.x * 256 + threadIdx.x) * 4;
    const float4 f = *(const float4*)(src + i);
    ushort4 o;
    o.x = f2bf(f.x); o.y = f2bf(f.y); o.z = f2bf(f.z); o.w = f2bf(f.w);
    *(ushort4*)(dst + i) = o;
}

// ---------------------------------------------------------------------------
// weights: fp32 768x768 [k][n] -> bf16 transposed [n][k] (LDS 32x32 tiles)
// ---------------------------------------------------------------------------
__global__ __launch_bounds__(256) void conv_wT_kernel(
    const float* __restrict__ wq, const float* __restrict__ wk,
    const float* __restrict__ wv, const float* __restrict__ wo,
    unsigned short* __restrict__ wqT, unsigned short* __restrict__ wkT,
    unsigned short* __restrict__ wvT, unsigned short* __restrict__ woT)
{
    const int z = blockIdx.z;
    const float* W = (z == 0) ? wq : (z == 1) ? wk : (z == 2) ? wv : wo;
    unsigned short* WT = (z == 0) ? wqT : (z == 1) ? wkT : (z == 2) ? wvT : woT;
    __shared__ float tile[32][33];
    const int tx = threadIdx.x & 31, ty = threadIdx.x >> 5;
    const int k0 = blockIdx.y * 32, n0 = blockIdx.x * 32;
#pragma unroll
    for (int r = 0; r < 4; ++r)
        tile[ty + r * 8][tx] = W[(size_t)(k0 + ty + r * 8) * DD + n0 + tx];
    __syncthreads();
#pragma unroll
    for (int r = 0; r < 4; ++r)
        WT[(size_t)(n0 + ty + r * 8) * DD + k0 + tx] = f2bf(tile[tx][ty + r * 8]);
}

// ---------------------------------------------------------------------------
// V head-split transpose: vh (B,H,S,DEP) bf16 -> vhT (B,H,DEP,S) bf16.
// Moves the transpose out of the attention hot loop (was 8-way-conflicted
// scalar LDS writes there). 12.6 MB each way, ~5 us.
// ---------------------------------------------------------------------------
__global__ __launch_bounds__(256) void transpose_v_kernel(
    const unsigned short* __restrict__ vh, unsigned short* __restrict__ vhT)
{
    const int t = blockIdx.x, bh = blockIdx.y;
    const unsigned short* src = vh + ((size_t)bh * SS + (size_t)t * 64) * DEP;
    unsigned short* dst = vhT + (size_t)bh * DEP * SS + (size_t)t * 64;
    __shared__ unsigned short tile[64][72];
    const int tid = threadIdx.x;
#pragma unroll
    for (int it = 0; it < 2; ++it) {
        const int f = it * 256 + tid;
        const int row = f >> 3, c8 = (f & 7) * 8;
        *(float4*)&tile[row][c8] = *(const float4*)&src[(size_t)row * DEP + c8];
    }
    __syncthreads();
#pragma unroll
    for (int it = 0; it < 2; ++it) {
        const int f = it * 256 + tid;
        const int drow = f >> 3, s8 = (f & 7) * 8;
        short8 o;
#pragma unroll
        for (int j = 0; j < 8; ++j) o[j] = (short)tile[s8 + j][drow];
        *(short8*)&dst[(size_t)drow * SS + s8] = o;
    }
}

// ---------------------------------------------------------------------------
// bf16 MFMA GEMM 128x128, BK=64, 4 waves (2x2, 64x64 each).
// A: (M x 768) bf16 row-major; BT: (768 x 768) bf16 [n][k].
// QKV variant writes bf16 head-split (B,H,S,DEP); out variant writes fp32.
// ---------------------------------------------------------------------------
__global__ __launch_bounds__(256) void qkv_gemm_kernel(
    const unsigned short* __restrict__ qb, const unsigned short* __restrict__ kb,
    const unsigned short* __restrict__ vb,
    const unsigned short* __restrict__ wqT, const unsigned short* __restrict__ wkT,
    const unsigned short* __restrict__ wvT,
    const float* __restrict__ bq, const float* __restrict__ bk,
    const float* __restrict__ bv,
    unsigned short* __restrict__ qh, unsigned short* __restrict__ kh,
    unsigned short* __restrict__ vh)
{
    const int z = blockIdx.z;
    const unsigned short* A  = (z == 0) ? qb  : (z == 1) ? kb  : vb;
    const unsigned short* BT = (z == 0) ? wqT : (z == 1) ? wkT : wvT;
    const float* bias        = (z == 0) ? bq  : (z == 1) ? bk  : bv;
    unsigned short* Y        = (z == 0) ? qh  : (z == 1) ? kh  : vh;

    const int m0 = blockIdx.y * 128, n0 = blockIdx.x * 128;
    const int tid = threadIdx.x;
    const int wave = tid >> 6, lane = tid & 63;
    const int quad = lane >> 4, l16 = lane & 15;
    const int wm = (wave & 1) * 64, wn = (wave >> 1) * 64;

    __shared__ unsigned short aS[128][72];
    __shared__ unsigned short bS[128][72];

    floatx4 acc[4][4];
#pragma unroll
    for (int i = 0; i < 4; ++i)
#pragma unroll
        for (int j = 0; j < 4; ++j) acc[i][j] = (floatx4){0.f, 0.f, 0.f, 0.f};

    for (int k0 = 0; k0 < DD; k0 += 64) {
        __syncthreads();
#pragma unroll
        for (int it = 0; it < 4; ++it) {
            const int f = it * 256 + tid;
            const int row = f >> 3, c8 = (f & 7) * 8;
            *(float4*)&aS[row][c8] = *(const float4*)&A[(size_t)(m0 + row) * DD + k0 + c8];
            *(float4*)&bS[row][c8] = *(const float4*)&BT[(size_t)(n0 + row) * DD + k0 + c8];
        }
        __syncthreads();
        short8 a[2][4], b[2][4];
#pragma unroll
        for (int kc = 0; kc < 2; ++kc)
#pragma unroll
            for (int t = 0; t < 4; ++t) {
                a[kc][t] = *(const short8*)&aS[wm + t * 16 + l16][kc * 32 + quad * 8];
                b[kc][t] = *(const short8*)&bS[wn + t * 16 + l16][kc * 32 + quad * 8];
            }
#pragma unroll
        for (int kc = 0; kc < 2; ++kc)
#pragma unroll
            for (int tm = 0; tm < 4; ++tm)
#pragma unroll
                for (int tn = 0; tn < 4; ++tn)
                    acc[tm][tn] = __builtin_amdgcn_mfma_f32_16x16x32_bf16(
                        a[kc][tm], b[kc][tn], acc[tm][tn], 0, 0, 0);
    }

#pragma unroll
    for (int tm = 0; tm < 4; ++tm)
#pragma unroll
        for (int tn = 0; tn < 4; ++tn)
#pragma unroll
            for (int r = 0; r < 4; ++r) {
                const int row = m0 + wm + tm * 16 + quad * 4 + r;
                const int col = n0 + wn + tn * 16 + l16;
                const float val = acc[tm][tn][r] + bias[col];
                const int bi = row >> 10, s = row & 1023;
                const int hh = col >> 6, dp = col & 63;
                Y[(((size_t)bi * HH + hh) * SS + s) * DEP + dp] = f2bf(val);
            }
}

__global__ __launch_bounds__(256) void out_gemm_kernel(
    const unsigned short* __restrict__ A, const unsigned short* __restrict__ BT,
    const float* __restrict__ bias, float* __restrict__ Y)
{
    const int m0 = blockIdx.y * 128, n0 = blockIdx.x * 128;
    const int tid = threadIdx.x;
    const int wave = tid >> 6, lane = tid & 63;
    const int quad = lane >> 4, l16 = lane & 15;
    const int wm = (wave & 1) * 64, wn = (wave >> 1) * 64;

    __shared__ unsigned short aS[128][72];
    __shared__ unsigned short bS[128][72];

    floatx4 acc[4][4];
#pragma unroll
    for (int i = 0; i < 4; ++i)
#pragma unroll
        for (int j = 0; j < 4; ++j) acc[i][j] = (floatx4){0.f, 0.f, 0.f, 0.f};

    for (int k0 = 0; k0 < DD; k0 += 64) {
        __syncthreads();
#pragma unroll
        for (int it = 0; it < 4; ++it) {
            const int f = it * 256 + tid;
            const int row = f >> 3, c8 = (f & 7) * 8;
            *(float4*)&aS[row][c8] = *(const float4*)&A[(size_t)(m0 + row) * DD + k0 + c8];
            *(float4*)&bS[row][c8] = *(const float4*)&BT[(size_t)(n0 + row) * DD + k0 + c8];
        }
        __syncthreads();
        short8 a[2][4], b[2][4];
#pragma unroll
        for (int kc = 0; kc < 2; ++kc)
#pragma unroll
            for (int t = 0; t < 4; ++t) {
                a[kc][t] = *(const short8*)&aS[wm + t * 16 + l16][kc * 32 + quad * 8];
                b[kc][t] = *(const short8*)&bS[wn + t * 16 + l16][kc * 32 + quad * 8];
            }
#pragma unroll
        for (int kc = 0; kc < 2; ++kc)
#pragma unroll
            for (int tm = 0; tm < 4; ++tm)
#pragma unroll
                for (int tn = 0; tn < 4; ++tn)
                    acc[tm][tn] = __builtin_amdgcn_mfma_f32_16x16x32_bf16(
                        a[kc][tm], b[kc][tn], acc[tm][tn], 0, 0, 0);
    }

#pragma unroll
    for (int tm = 0; tm < 4; ++tm)
#pragma unroll
        for (int tn = 0; tn < 4; ++tn)
#pragma unroll
            for (int r = 0; r < 4; ++r) {
                const int row = m0 + wm + tm * 16 + quad * 4 + r;
                const int col = n0 + wn + tn * 16 + l16;
                Y[(size_t)row * DD + col] = acc[tm][tn][r] + bias[col];
            }
}

// ---------------------------------------------------------------------------
// Fused attention, bf16 MFMA. Block = (b,h,64 q-rows); wave w owns rows
// w*16..w*16+15. Sweep A: QK^T via MFMA + online max/sum. Sweep B: recompute
// scores, write fp32 attn (LDS-staged, coalesced), P->bf16 LDS, P@V via MFMA.
//
// v2 changes vs v1 (theory: latency-bound, scalar VMEM + LDS conflicts):
//   - adjoin tile staged to LDS with float4 loads (both sweeps); the fp32 p
//     value is written IN PLACE over its adjoin element, then stored to
//     attn with coalesced float4 (was: 512 scalar 4B loads + 256 scalar
//     4B stores per thread).
//   - V^T comes pre-transposed from transpose_v_kernel; staged with float4
//     (was: 16 scalar u16 LDS writes/thread/tile at 8-way bank conflict).
//   - mask row staged to LDS once.
//   - XCD swizzle: 1536 blocks = 8 XCDs x 192; each XCD owns one batch b,
//     so its 4MB adjoin panel lives in that XCD's L2.
//   - s_setprio(1) around MFMA clusters (T5, +4-7% measured on attn).
// LDS 48KB -> 3 blocks/CU (12 waves/CU), same as measured occupancy before.
// ---------------------------------------------------------------------------
__global__ __launch_bounds__(256) void attn_kernel(
    const unsigned short* __restrict__ qh, const unsigned short* __restrict__ kh,
    const unsigned short* __restrict__ vhT, const float* __restrict__ mask,
    const float* __restrict__ adjoin, float* __restrict__ attn_out,
    unsigned short* __restrict__ concat)
{
    // XCD-aware swizzle: nwg=1536, 1536%8==0 -> bijective. Each XCD gets
    // 192 consecutive logical blocks = exactly one batch b.
    const int bid = (blockIdx.x & 7) * 192 + (blockIdx.x >> 3);
    const int rb = bid & 15;
    const int h  = (bid >> 4) % HH;
    const int b  = bid / (16 * HH);
    const int r0 = rb * 64;

    const unsigned short* qbp = qh + ((size_t)(b * HH + h)) * SS * DEP;
    const unsigned short* kbp = kh + ((size_t)(b * HH + h)) * SS * DEP;
    const unsigned short* vTp = vhT + ((size_t)(b * HH + h)) * DEP * SS;
    const float* adj = adjoin + (size_t)b * SS * SS;
    const float* mk  = mask + (size_t)b * SS;
    float* attn = attn_out + ((size_t)(b * HH + h)) * SS * SS;

    __shared__ unsigned short kS[64][72];    // K tile (both sweeps)
    __shared__ unsigned short vS[64][72];    // V^T tile [dep][s-local] (sweep B)
    __shared__ unsigned short qpS[64][72];   // Q staging, then P bf16 (sweep B)
    __shared__ float adjS[64][68];           // adjoin tile fp32, then p fp32
    __shared__ float mS[SS];                 // mask row

    const int tid = threadIdx.x;
    const int wave = tid >> 6, lane = tid & 63;
    const int quad = lane >> 4, l16 = lane & 15;

    // stage Q once (64 rows x 64 deps bf16) + mask row once
#pragma unroll
    for (int it = 0; it < 2; ++it) {
        const int f = it * 256 + tid;
        const int row = f >> 3, c8 = (f & 7) * 8;
        *(float4*)&qpS[row][c8] = *(const float4*)&qbp[(size_t)(r0 + row) * DEP + c8];
    }
    *(float4*)&mS[tid * 4] = *(const float4*)&mk[tid * 4];
    __syncthreads();
    const short8 aq0 = *(const short8*)&qpS[wave * 16 + l16][quad * 8];
    const short8 aq1 = *(const short8*)&qpS[wave * 16 + l16][32 + quad * 8];

    float m_[4], l_[4];
#pragma unroll
    for (int r = 0; r < 4; ++r) { m_[r] = -INFINITY; l_[r] = 0.f; }

    // ---------------- Sweep A: online max/sum ----------------
    for (int t = 0; t < 16; ++t) {
        __syncthreads();
#pragma unroll
        for (int it = 0; it < 2; ++it) {
            const int f = it * 256 + tid;
            const int row = f >> 3, c8 = (f & 7) * 8;
            *(float4*)&kS[row][c8] = *(const float4*)&kbp[(size_t)(t * 64 + row) * DEP + c8];
        }
#pragma unroll
        for (int it = 0; it < 4; ++it) {
            const int row = it * 16 + (tid >> 4), c4 = (tid & 15) * 4;
            *(float4*)&adjS[row][c4] = *(const float4*)&adj[(size_t)(r0 + row) * SS + t * 64 + c4];
        }
        __syncthreads();

        floatx4 sc[4];
        __builtin_amdgcn_s_setprio(1);
#pragma unroll
        for (int tn = 0; tn < 4; ++tn) {
            const short8 b0 = *(const short8*)&kS[tn * 16 + l16][quad * 8];
            const short8 b1 = *(const short8*)&kS[tn * 16 + l16][32 + quad * 8];
            floatx4 z = (floatx4){0.f, 0.f, 0.f, 0.f};
            z = __builtin_amdgcn_mfma_f32_16x16x32_bf16(aq0, b0, z, 0, 0, 0);
            z = __builtin_amdgcn_mfma_f32_16x16x32_bf16(aq1, b1, z, 0, 0, 0);
            sc[tn] = z;
        }
        __builtin_amdgcn_s_setprio(0);

        float lg[4][4];
#pragma unroll
        for (int tn = 0; tn < 4; ++tn) {
            const int cl = tn * 16 + l16;
            const float mv = -1e9f * mS[t * 64 + cl];
#pragma unroll
            for (int r = 0; r < 4; ++r) {
                const int lr = wave * 16 + quad * 4 + r;
                lg[tn][r] = sc[tn][r] * 0.125f + mv + adjS[lr][cl];
            }
        }
#pragma unroll
        for (int r = 0; r < 4; ++r) {
            float tmax = fmaxf(fmaxf(lg[0][r], lg[1][r]), fmaxf(lg[2][r], lg[3][r]));
            tmax = fmaxf(tmax, __shfl_xor(tmax, 1));
            tmax = fmaxf(tmax, __shfl_xor(tmax, 2));
            tmax = fmaxf(tmax, __shfl_xor(tmax, 4));
            tmax = fmaxf(tmax, __shfl_xor(tmax, 8));
            const float mn = fmaxf(m_[r], tmax);
            float ps = __expf(lg[0][r] - mn) + __expf(lg[1][r] - mn)
                     + __expf(lg[2][r] - mn) + __expf(lg[3][r] - mn);
            ps += __shfl_xor(ps, 1);
            ps += __shfl_xor(ps, 2);
            ps += __shfl_xor(ps, 4);
            ps += __shfl_xor(ps, 8);
            l_[r] = l_[r] * __expf(m_[r] - mn) + ps;
            m_[r] = mn;
        }
    }

    float invl[4];
#pragma unroll
    for (int r = 0; r < 4; ++r) invl[r] = 1.0f / l_[r];

    floatx4 oacc[4];
#pragma unroll
    for (int tn = 0; tn < 4; ++tn) oacc[tn] = (floatx4){0.f, 0.f, 0.f, 0.f};

    // ---------------- Sweep B: attn write + P@V ----------------
    for (int t = 0; t < 16; ++t) {
        __syncthreads();
#pragma unroll
        for (int it = 0; it < 2; ++it) {
            const int f = it * 256 + tid;
            const int row = f >> 3, c8 = (f & 7) * 8;
            *(float4*)&kS[row][c8] = *(const float4*)&kbp[(size_t)(t * 64 + row) * DEP + c8];
            *(float4*)&vS[row][c8] = *(const float4*)&vTp[(size_t)row * SS + t * 64 + c8];
        }
#pragma unroll
        for (int it = 0; it < 4; ++it) {
            const int row = it * 16 + (tid >> 4), c4 = (tid & 15) * 4;
            *(float4*)&adjS[row][c4] = *(const float4*)&adj[(size_t)(r0 + row) * SS + t * 64 + c4];
        }
        __syncthreads();

        floatx4 sc[4];
        __builtin_amdgcn_s_setprio(1);
#pragma unroll
        for (int tn = 0; tn < 4; ++tn) {
            const short8 b0 = *(const short8*)&kS[tn * 16 + l16][quad * 8];
            const short8 b1 = *(const short8*)&kS[tn * 16 + l16][32 + quad * 8];
            floatx4 z = (floatx4){0.f, 0.f, 0.f, 0.f};
            z = __builtin_amdgcn_mfma_f32_16x16x32_bf16(aq0, b0, z, 0, 0, 0);
            z = __builtin_amdgcn_mfma_f32_16x16x32_bf16(aq1, b1, z, 0, 0, 0);
            sc[tn] = z;
        }
        __builtin_amdgcn_s_setprio(0);

#pragma unroll
        for (int tn = 0; tn < 4; ++tn) {
            const int cl = tn * 16 + l16;
            const float mv = -1e9f * mS[t * 64 + cl];
#pragma unroll
            for (int r = 0; r < 4; ++r) {
                const int lr = wave * 16 + quad * 4 + r;
                const float lgv = sc[tn][r] * 0.125f + mv + adjS[lr][cl];
                const float p = __expf(lgv - m_[r]) * invl[r];
                adjS[lr][cl] = p;            // in-place: same element, same owner
                qpS[lr][cl] = f2bf(p);
            }
        }
        __syncthreads();

        const short8 ap0 = *(const short8*)&qpS[wave * 16 + l16][quad * 8];
        const short8 ap1 = *(const short8*)&qpS[wave * 16 + l16][32 + quad * 8];
        __builtin_amdgcn_s_setprio(1);
#pragma unroll
        for (int tn = 0; tn < 4; ++tn) {
            const short8 bv0 = *(const short8*)&vS[tn * 16 + l16][quad * 8];
            const short8 bv1 = *(const short8*)&vS[tn * 16 + l16][32 + quad * 8];
            oacc[tn] = __builtin_amdgcn_mfma_f32_16x16x32_bf16(ap0, bv0, oacc[tn], 0, 0, 0);
            oacc[tn] = __builtin_amdgcn_mfma_f32_16x16x32_bf16(ap1, bv1, oacc[tn], 0, 0, 0);
        }
        __builtin_amdgcn_s_setprio(0);

        // coalesced attn store (float4 per lane, 1KiB per wave instr)
#pragma unroll
        for (int it = 0; it < 4; ++it) {
            const int row = it * 16 + (tid >> 4), c4 = (tid & 15) * 4;
            const float4 pv = *(const float4*)&adjS[row][c4];
            *(float4*)&attn[(size_t)(r0 + row) * SS + t * 64 + c4] = pv;
        }
    }

#pragma unroll
    for (int tn = 0; tn < 4; ++tn)
#pragma unroll
        for (int r = 0; r < 4; ++r) {
            const int s = r0 + wave * 16 + quad * 4 + r;
            const int dp = tn * 16 + l16;
            concat[((size_t)b * SS + s) * DD + h * DEP + dp] = f2bf(oacc[tn][r]);
        }
}

// ---------------------------------------------------------------------------
extern "C" void kernel_launch(void* const* d_in, const int* in_sizes, int n_in,
                              void* d_out, int out_size, void* d_ws, size_t ws_size,
                              hipStream_t stream)
{
    (void)in_sizes; (void)n_in; (void)out_size; (void)ws_size;

    const float* v      = (const float*)d_in[0];
    const float* k      = (const float*)d_in[1];
    const float* q      = (const float*)d_in[2];
    const float* mask   = (const float*)d_in[3];
    const float* adjoin = (const float*)d_in[4];
    const float* wq     = (const float*)d_in[5];
    const float* bq     = (const float*)d_in[6];
    const float* wk     = (const float*)d_in[7];
    const float* bk     = (const float*)d_in[8];
    const float* wv     = (const float*)d_in[9];
    const float* bv     = (const float*)d_in[10];
    const float* wo     = (const float*)d_in[11];
    const float* bo     = (const float*)d_in[12];

    float* out  = (float*)d_out;                 // (B,S,D) fp32
    float* attn = out + (size_t)BB * SS * DD;    // (B,H,S,S) fp32

    const size_t N1 = (size_t)BB * SS * DD;      // 6,291,456
    const size_t NW = (size_t)DD * DD;           // 589,824
    unsigned short* ws = (unsigned short*)d_ws;
    unsigned short* qb      = ws;                // bf16 (B*S, D); dead after qkv_gemm
    unsigned short* kb      = ws + N1;
    unsigned short* vb      = ws + 2 * N1;
    unsigned short* qhb     = ws + 3 * N1;       // bf16 (B,H,S,DEP)
    unsigned short* khb     = ws + 4 * N1;
    unsigned short* vhb     = ws + 5 * N1;
    unsigned short* concatb = ws + 6 * N1;       // bf16 (B,S,D)
    unsigned short* wqT     = ws + 7 * N1;       // bf16 (768,768) [n][k]
    unsigned short* wkT     = wqT + NW;
    unsigned short* wvT     = wkT + NW;
    unsigned short* woT     = wvT + NW;
    unsigned short* vhT     = qb;                // bf16 (B,H,DEP,S), aliases dead qb

    conv_inputs_kernel<<<dim3((unsigned)(N1 / 4 / 256), 3), 256, 0, stream>>>(
        q, k, v, qb, kb, vb);
    conv_wT_kernel<<<dim3(24, 24, 4), 256, 0, stream>>>(
        wq, wk, wv, wo, wqT, wkT, wvT, woT);

    qkv_gemm_kernel<<<dim3(DD / 128, (BB * SS) / 128, 3), 256, 0, stream>>>(
        qb, kb, vb, wqT, wkT, wvT, bq, bk, bv, qhb, khb, vhb);

    transpose_v_kernel<<<dim3(SS / 64, BB * HH), 256, 0, stream>>>(vhb, vhT);

    attn_kernel<<<dim3(16 * HH * BB), 256, 0, stream>>>(
        qhb, khb, vhT, mask, adjoin, attn, concatb);

    out_gemm_kernel<<<dim3(DD / 128, (BB * SS) / 128), 256, 0, stream>>>(
        concatb, woT, bo, out);
}